// Round 2
// baseline (927.713 us; speedup 1.0000x reference)
//
#include <hip/hip_runtime.h>

typedef __bf16 bf16x8 __attribute__((ext_vector_type(8)));
typedef float  f32x4  __attribute__((ext_vector_type(4)));

#define N_CELLS 8000
#define N_GENES 8000
#define N_REG   20000
#define NF      100
#define KP      128     // padded K (factors) for MFMA
#define NFT     112     // padded factor count for ASr output (7*16)

static __device__ __forceinline__ unsigned short f2bf_bits(float f) {
  unsigned u = __builtin_bit_cast(unsigned, f);
  u = (u + 0x7FFFu + ((u >> 16) & 1u)) >> 16;   // RNE
  return (unsigned short)u;
}
static __device__ __forceinline__ __bf16 f2bf(float f) {
  unsigned short h = f2bf_bits(f);
  return __builtin_bit_cast(__bf16, h);
}
static __device__ __forceinline__ float bf2f(unsigned short s) {
  unsigned u = ((unsigned)s) << 16;
  return __builtin_bit_cast(float, u);
}

// ---------------- softmax(row of 100) then T = Srow @ W, bf16 out padded to 128
__global__ void softmax_matT_kernel(const float* __restrict__ C,
                                    const float* __restrict__ W,
                                    unsigned short* __restrict__ outT) {
  __shared__ float red[128];
  __shared__ float srow[NF];
  int i = blockIdx.x, t = threadIdx.x;
  float v = (t < NF) ? C[i * NF + t] : -3.0e38f;
  red[t] = v; __syncthreads();
  #pragma unroll
  for (int s = 64; s > 0; s >>= 1) { if (t < s) red[t] = fmaxf(red[t], red[t + s]); __syncthreads(); }
  float m = red[0]; __syncthreads();
  float e = (t < NF) ? __expf(v - m) : 0.f;
  red[t] = e; __syncthreads();
  #pragma unroll
  for (int s = 64; s > 0; s >>= 1) { if (t < s) red[t] += red[t + s]; __syncthreads(); }
  float inv = 1.f / red[0];
  if (t < NF) srow[t] = e * inv;
  __syncthreads();
  if (t < NF) {
    float acc = 0.f;
    #pragma unroll 4
    for (int k = 0; k < NF; ++k) acc = fmaf(srow[k], W[k * NF + t], acc);
    outT[i * KP + t] = f2bf_bits(acc);
  } else {
    outT[i * KP + t] = 0;
  }
}

// ---------------- softmax only; row-major bf16 [row][128]; optional transposed [112][nrows]
__global__ void softmax_kernel(const float* __restrict__ C,
                               unsigned short* __restrict__ outR,
                               unsigned short* __restrict__ outT, int nrows) {
  __shared__ float red[128];
  int i = blockIdx.x, t = threadIdx.x;
  float v = (t < NF) ? C[i * NF + t] : -3.0e38f;
  red[t] = v; __syncthreads();
  #pragma unroll
  for (int s = 64; s > 0; s >>= 1) { if (t < s) red[t] = fmaxf(red[t], red[t + s]); __syncthreads(); }
  float m = red[0]; __syncthreads();
  float e = (t < NF) ? __expf(v - m) : 0.f;
  red[t] = e; __syncthreads();
  #pragma unroll
  for (int s = 64; s > 0; s >>= 1) { if (t < s) red[t] += red[t + s]; __syncthreads(); }
  float inv = 1.f / red[0];
  unsigned short b = (t < NF) ? f2bf_bits(e * inv) : (unsigned short)0;
  outR[i * KP + t] = b;
  if (outT != nullptr && t < NFT) outT[t * nrows + i] = b;  // rows 100..111 get zeros
}

// ---------------- fused residual SSE: sum((X - Tm@Sm^T - bcol - brow)^2)
// Tm: [8000][128] bf16, Sm: [N][128] bf16. block=256 (4 waves, 2x2 of 32x32).
__global__ __launch_bounds__(256) void resid_kernel(
    const float* __restrict__ X,
    const unsigned short* __restrict__ Tm,
    const unsigned short* __restrict__ Sm,
    const float* __restrict__ bcol,
    const float* __restrict__ brow,
    int N, float* __restrict__ buckets) {
  int t = threadIdx.x;
  int wid = t >> 6, lane = t & 63;
  int lr = lane & 15, lg = lane >> 4;
  int i0 = blockIdx.x * 64 + (wid >> 1) * 32;
  int j0 = blockIdx.y * 64 + (wid & 1) * 32;

  f32x4 zero = {0.f, 0.f, 0.f, 0.f};
  f32x4 acc[2][2] = {{zero, zero}, {zero, zero}};
  #pragma unroll
  for (int ks = 0; ks < 4; ++ks) {
    bf16x8 a[2], b[2];
    #pragma unroll
    for (int mi = 0; mi < 2; ++mi) {
      int row = i0 + mi * 16 + lr;
      a[mi] = *reinterpret_cast<const bf16x8*>(Tm + row * KP + ks * 32 + lg * 8);
    }
    #pragma unroll
    for (int ni = 0; ni < 2; ++ni) {
      int col = j0 + ni * 16 + lr;
      if (col >= N) col = N - 1;  // masked in epilogue
      b[ni] = *reinterpret_cast<const bf16x8*>(Sm + col * KP + ks * 32 + lg * 8);
    }
    #pragma unroll
    for (int mi = 0; mi < 2; ++mi) {
      #pragma unroll
      for (int ni = 0; ni < 2; ++ni)
        acc[mi][ni] = __builtin_amdgcn_mfma_f32_16x16x32_bf16(a[mi], b[ni], acc[mi][ni], 0, 0, 0);
    }
  }
  float sse = 0.f;
  #pragma unroll
  for (int mi = 0; mi < 2; ++mi) {
    int rbase = i0 + mi * 16 + lg * 4;
    #pragma unroll
    for (int ni = 0; ni < 2; ++ni) {
      int col = j0 + ni * 16 + lr;
      if (col < N) {
        float bc = bcol[col];
        #pragma unroll
        for (int j = 0; j < 4; ++j) {
          int row = rbase + j;
          float e = X[row * N + col] - acc[mi][ni][j] - bc - brow[row];
          sse = fmaf(e, e, sse);
        }
      }
    }
  }
  #pragma unroll
  for (int off = 32; off > 0; off >>= 1) sse += __shfl_xor(sse, off);
  __shared__ float wsum[4];
  if (lane == 0) wsum[wid] = sse;
  __syncthreads();
  if (t == 0)
    atomicAdd(&buckets[(blockIdx.x * gridDim.y + blockIdx.y) & 63],
              wsum[0] + wsum[1] + wsum[2] + wsum[3]);
}

// ---------------- ASr = A(f32,[8000][20000]) @ Sr  via SrT bf16 [112][20000]; split-K atomics
__global__ __launch_bounds__(128) void asr_kernel(
    const float* __restrict__ A,
    const unsigned short* __restrict__ SrT,
    float* __restrict__ ASr) {
  int t = threadIdx.x;
  int w = t >> 6, lane = t & 63;
  int lr = lane & 15, lg = lane >> 4;
  int g0 = blockIdx.x * 64 + w * 32;
  int kbase = blockIdx.y * 800;

  f32x4 zero = {0.f, 0.f, 0.f, 0.f};
  f32x4 acc[2][7];
  #pragma unroll
  for (int mi = 0; mi < 2; ++mi)
    #pragma unroll
    for (int ni = 0; ni < 7; ++ni) acc[mi][ni] = zero;

  for (int k0 = kbase; k0 < kbase + 800; k0 += 32) {
    bf16x8 a[2];
    #pragma unroll
    for (int mi = 0; mi < 2; ++mi) {
      const float* pa = A + (g0 + mi * 16 + lr) * N_REG + k0 + lg * 8;
      f32x4 v0 = *reinterpret_cast<const f32x4*>(pa);
      f32x4 v1 = *reinterpret_cast<const f32x4*>(pa + 4);
      bf16x8 af;
      af[0] = f2bf(v0[0]); af[1] = f2bf(v0[1]); af[2] = f2bf(v0[2]); af[3] = f2bf(v0[3]);
      af[4] = f2bf(v1[0]); af[5] = f2bf(v1[1]); af[6] = f2bf(v1[2]); af[7] = f2bf(v1[3]);
      a[mi] = af;
    }
    #pragma unroll
    for (int ni = 0; ni < 7; ++ni) {
      bf16x8 b = *reinterpret_cast<const bf16x8*>(SrT + (ni * 16 + lr) * N_REG + k0 + lg * 8);
      acc[0][ni] = __builtin_amdgcn_mfma_f32_16x16x32_bf16(a[0], b, acc[0][ni], 0, 0, 0);
      acc[1][ni] = __builtin_amdgcn_mfma_f32_16x16x32_bf16(a[1], b, acc[1][ni], 0, 0, 0);
    }
  }
  #pragma unroll
  for (int mi = 0; mi < 2; ++mi) {
    int gb = g0 + mi * 16 + lg * 4;
    #pragma unroll
    for (int ni = 0; ni < 7; ++ni) {
      int f = ni * 16 + lr;
      #pragma unroll
      for (int j = 0; j < 4; ++j)
        atomicAdd(&ASr[(gb + j) * NFT + f], acc[mi][ni][j]);
    }
  }
}

// ---------------- loss3 pieces: dot(Ag,Ar), |Ag|^2, |Ar|^2 (single block)
__global__ void l3_kernel(const float* __restrict__ Ag, const float* __restrict__ Ar,
                          float* __restrict__ accv) {
  int t = threadIdx.x;
  float d = 0.f, na = 0.f, nr = 0.f;
  for (int i = t; i < NF * NF; i += 256) {
    float a = Ag[i], r = Ar[i];
    d = fmaf(a, r, d); na = fmaf(a, a, na); nr = fmaf(r, r, nr);
  }
  #pragma unroll
  for (int off = 32; off > 0; off >>= 1) {
    d += __shfl_xor(d, off); na += __shfl_xor(na, off); nr += __shfl_xor(nr, off);
  }
  __shared__ float r3[3][4];
  int lane = t & 63, w = t >> 6;
  if (lane == 0) { r3[0][w] = d; r3[1][w] = na; r3[2][w] = nr; }
  __syncthreads();
  if (t == 0) {
    accv[2] = r3[0][0] + r3[0][1] + r3[0][2] + r3[0][3];
    accv[3] = r3[1][0] + r3[1][1] + r3[1][2] + r3[1][3];
    accv[4] = r3[2][0] + r3[2][1] + r3[2][2] + r3[2][3];
  }
}

// ---------------- loss4 pieces: dot(Sg,ASr), |Sg|^2, |ASr|^2
__global__ void l4red_kernel(const unsigned short* __restrict__ Sgbf,
                             const float* __restrict__ ASr,
                             float* __restrict__ accv) {
  int t = blockIdx.x * blockDim.x + threadIdx.x;
  float d = 0.f, n1 = 0.f, n2 = 0.f;
  for (int idx = t; idx < N_GENES * NFT; idx += gridDim.x * blockDim.x) {
    int g = idx / NFT, f = idx - g * NFT;
    float sg = bf2f(Sgbf[g * KP + f]);
    float av = ASr[idx];
    d = fmaf(sg, av, d); n1 = fmaf(sg, sg, n1); n2 = fmaf(av, av, n2);
  }
  #pragma unroll
  for (int off = 32; off > 0; off >>= 1) {
    d += __shfl_xor(d, off); n1 += __shfl_xor(n1, off); n2 += __shfl_xor(n2, off);
  }
  __shared__ float r3[3][4];
  int lane = threadIdx.x & 63, w = threadIdx.x >> 6;
  if (lane == 0) { r3[0][w] = d; r3[1][w] = n1; r3[2][w] = n2; }
  __syncthreads();
  if (threadIdx.x == 0) {
    atomicAdd(&accv[5], r3[0][0] + r3[0][1] + r3[0][2] + r3[0][3]);
    atomicAdd(&accv[6], r3[1][0] + r3[1][1] + r3[1][2] + r3[1][3]);
    atomicAdd(&accv[7], r3[2][0] + r3[2][1] + r3[2][2] + r3[2][3]);
  }
}

// ---------------- finalize
__global__ void fin_kernel(const float* __restrict__ accv,
                           const float* __restrict__ bk1,
                           const float* __restrict__ bk2,
                           const float* __restrict__ alpha,
                           float* __restrict__ out) {
  if (threadIdx.x == 0) {
    float s1 = 0.f, s2 = 0.f;
    for (int i = 0; i < 64; ++i) { s1 += bk1[i]; s2 += bk2[i]; }
    float loss1 = s1 / 64000000.0f;
    float loss2 = s2 / 160000000.0f;
    float loss3 = -accv[2] / (sqrtf(accv[3]) * sqrtf(accv[4]));
    float loss4 = -accv[5] / (sqrtf(accv[6]) * sqrtf(accv[7]));
    float l1 = alpha[0] * loss1, l2 = alpha[1] * loss2;
    float l3 = alpha[2] * loss3, l4 = alpha[3] * loss4;
    out[0] = l1 + l2 + l3 + l4;
    out[1] = l1; out[2] = l2; out[3] = l3; out[4] = l4;
  }
}

// ws layout (bytes):
//   0        : ASr f32 [8000][112]            (3,584,000)
//   3,584,000: buckets1 f32[64]
//   3,584,256: buckets2 f32[64]
//   3,584,512: accv f32[16]
//   3,585,024: T1 bf16 [8000][128]            (2,048,000)
//   5,633,024: T2 bf16 [8000][128]            (2,048,000)
//   7,681,024: Sg bf16 [8000][128]            (2,048,000)
//   9,729,024: Sr bf16 [20000][128]           (5,120,000)
//  14,849,024: SrT bf16 [112][20000]          (4,480,000)
//  total ~19.4 MB

extern "C" void kernel_launch(void* const* d_in, const int* in_sizes, int n_in,
                              void* d_out, int out_size, void* d_ws, size_t ws_size,
                              hipStream_t stream) {
  const float* G  = (const float*)d_in[0];
  const float* R  = (const float*)d_in[1];
  const float* A  = (const float*)d_in[2];
  const float* C1 = (const float*)d_in[3];
  const float* C2 = (const float*)d_in[4];
  const float* Cg = (const float*)d_in[5];
  const float* Cr = (const float*)d_in[6];
  const float* Ag = (const float*)d_in[7];
  const float* Ar = (const float*)d_in[8];
  const float* bg = (const float*)d_in[9];
  const float* br = (const float*)d_in[10];
  const float* b1 = (const float*)d_in[11];
  const float* b2 = (const float*)d_in[12];
  const float* alpha = (const float*)d_in[13];

  char* ws = (char*)d_ws;
  float* ASr            = (float*)(ws + 0);
  float* buckets1       = (float*)(ws + 3584000);
  float* buckets2       = (float*)(ws + 3584256);
  float* accv           = (float*)(ws + 3584512);
  unsigned short* T1    = (unsigned short*)(ws + 3585024);
  unsigned short* T2    = (unsigned short*)(ws + 5633024);
  unsigned short* Sg    = (unsigned short*)(ws + 7681024);
  unsigned short* Sr    = (unsigned short*)(ws + 9729024);
  unsigned short* SrT   = (unsigned short*)(ws + 14849024);

  hipMemsetAsync(d_ws, 0, 3585024, stream);  // ASr + buckets + accv

  softmax_matT_kernel<<<N_CELLS, 128, 0, stream>>>(C1, Ag, T1);
  softmax_matT_kernel<<<N_CELLS, 128, 0, stream>>>(C2, Ar, T2);
  softmax_kernel<<<N_GENES, 128, 0, stream>>>(Cg, Sg, (unsigned short*)nullptr, 0);
  softmax_kernel<<<N_REG, 128, 0, stream>>>(Cr, Sr, SrT, N_REG);

  resid_kernel<<<dim3(125, 125), 256, 0, stream>>>(G, T1, Sg, bg, b1, N_GENES, buckets1);
  resid_kernel<<<dim3(125, 313), 256, 0, stream>>>(R, T2, Sr, br, b2, N_REG, buckets2);

  asr_kernel<<<dim3(125, 25), 128, 0, stream>>>(A, SrT, ASr);

  l3_kernel<<<1, 256, 0, stream>>>(Ag, Ar, accv);
  l4red_kernel<<<256, 256, 0, stream>>>(Sg, ASr, accv);
  fin_kernel<<<1, 64, 0, stream>>>(accv, buckets1, buckets2, alpha, (float*)d_out);
}